// Round 15
// baseline (35.994 us; speedup 1.0000x reference)
//
#include <hip/hip_runtime.h>

#define NBINS 10
#define NG 4
#define NH (NG * NBINS)      // 40
#define TPB 128              // 2 waves; each thread owns a private column
#define NBLOCKS 2048         // 8 blocks/CU * 256 CU
#define DROWS 20             // packed dword rows per copy (2 bins/dword)
#define INVUQ (1.0f / 63.0f)

typedef float f32x4 __attribute__((ext_vector_type(4)));
typedef int   i32x4 __attribute__((ext_vector_type(4)));

// Packed single RMW per sample, split across TWO DISTINCT LDS OBJECTS
// (even samples -> lhA, odd -> lhB). Distinct __shared__ variables provably
// don't alias, so the compiler can interleave the two RMW chains instead of
// serializing all 32 (data-dependent addresses within ONE array force a
// serial read->wait->add->write chain).
// Field packing (R11-validated): dword = hi:lo 16-bit fields, field =
// n<<11 | S_q, per-sample add = (2048 + uq)<<((row&1)*16), uq = round(u*63).
// <=19 samples/thread/copy -> field <= 19*2111 < 65536: no cross-field carry.
//   h[j] = 0.1*(n_j - U_j + U_{j-1}),  U = S_q/63
// Bank: addr = drow*TPB + tid -> bank = tid%32, 2 lanes/bank = conflict-free.
__device__ __forceinline__ void packone(float x, int g, int& adr, unsigned& val) {
    float ex = __expf(-x);                          // TRANS
    float rc = __builtin_amdgcn_rcpf(1.0f + ex);    // TRANS; sigmoid(x)
    float p  = __builtin_fmaf(rc, 10.0f, -0.001f);  // 10*(sigmoid - 1e-4)
    float fj = floorf(p);
    float u  = p - fj;                              // [0,1)
    int uq = (int)__builtin_fmaf(u, 63.0f, 0.5f);   // 0..63
    int j0 = max((int)fj, 0);                       // -1: P~2e-20, clamp
    int row = g * NBINS + j0;
    val = (2048u + (unsigned)uq) << ((row & 1) << 4);
    adr = row >> 1;
}

__global__ void __launch_bounds__(TPB, 4) wb_hist(const f32x4* __restrict__ acts,
                                                  const i32x4* __restrict__ labels,
                                                  const float* __restrict__ acts_s,
                                                  const int* __restrict__ labels_s,
                                                  float* __restrict__ parts,
                                                  int n4, int n, int nparts) {
    __shared__ unsigned lhA[DROWS * TPB];   // 10 KB  (distinct objects: no
    __shared__ unsigned lhB[DROWS * TPB];   // 10 KB   cross-chain aliasing)
    const int tid = threadIdx.x;
    const int span = gridDim.x * TPB * 8;   // float4s per chunk
    const int nchunk = (n4 + span - 1) / span;
    unsigned nAcc = 0, sAcc = 0;            // per-row accumulators (tid < NH)

    for (int c = 0; c < nchunk; ++c) {
        #pragma unroll
        for (int i = 0; i < DROWS; ++i) {
            lhA[i * TPB + tid] = 0u;
            lhB[i * TPB + tid] = 0u;
        }
        __syncthreads();

        const int base0 = c * span + blockIdx.x * (TPB * 8) + tid;
        if ((c + 1) * span <= n4 || ((c + 1) * span == ((n4 + TPB * 8 * (int)gridDim.x - 1)))) {}
        if (base0 + 7 * TPB < n4 && (c + 1) * span <= n4) {
            // ---- full chunk: phase-split (benchmark shape hits only this) ----
            f32x4 a[8]; i32x4 g[8];
            #pragma unroll
            for (int k = 0; k < 8; ++k) a[k] = __builtin_nontemporal_load(&acts[base0 + k * TPB]);
            #pragma unroll
            for (int k = 0; k < 8; ++k) g[k] = __builtin_nontemporal_load(&labels[base0 + k * TPB]);

            int adr[32]; unsigned val[32];
            #pragma unroll
            for (int k = 0; k < 8; ++k) {
                #pragma unroll
                for (int e = 0; e < 4; ++e)
                    packone(a[k][e], g[k][e], adr[k * 4 + e], val[k * 4 + e]);
            }
            // Two independent RMW chains, interleaved A/B
            #pragma unroll
            for (int s = 0; s < 32; s += 2) {
                lhA[adr[s]     * TPB + tid] += val[s];
                lhB[adr[s + 1] * TPB + tid] += val[s + 1];
            }
        } else {
            // ---- partial chunk (generic N): bounds-checked ----
            #pragma unroll
            for (int k = 0; k < 8; ++k) {
                int idx = base0 + k * TPB;
                if (idx < n4) {
                    f32x4 a = __builtin_nontemporal_load(&acts[idx]);
                    i32x4 g = __builtin_nontemporal_load(&labels[idx]);
                    #pragma unroll
                    for (int e = 0; e < 4; ++e) {
                        int adr1; unsigned val1;
                        packone(a[e], g[e], adr1, val1);
                        if (e & 1) lhB[adr1 * TPB + tid] += val1;
                        else       lhA[adr1 * TPB + tid] += val1;
                    }
                }
            }
        }

        // scalar tail for N % 4 != 0 (not hit for N = 8388608)
        if (c == nchunk - 1 && blockIdx.x == 0 && tid == 0) {
            for (int i = n4 * 4; i < n; ++i) {
                int adr1; unsigned val1;
                packone(acts_s[i], labels_s[i], adr1, val1);
                if (i & 1) lhB[adr1 * TPB] += val1;
                else       lhA[adr1 * TPB] += val1;
            }
        }
        __syncthreads();

        // per-chunk reduce: row tid, all 128 columns, both copies.
        // Row pairs (2r,2r+1) read the same dword (broadcast, free);
        // skewed column start keeps banks <=2-way.
        if (tid < NH) {
            const int sh = (tid & 1) << 4;
            const int dr = (tid >> 1) * TPB;
            unsigned nn = 0, ss = 0;
            for (int k = 0; k < TPB; ++k) {
                int colk = (tid + k) & (TPB - 1);
                unsigned fA = (lhA[dr + colk] >> sh) & 0xFFFFu;
                unsigned fB = (lhB[dr + colk] >> sh) & 0xFFFFu;
                nn += (fA >> 11) + (fB >> 11);
                ss += (fA & 0x7FFu) + (fB & 0x7FFu);
            }
            nAcc += nn; sAcc += ss;
        }
        if (c + 1 < nchunk) __syncthreads();   // protect re-zero
    }

    // fold U_{j-1} via shfl_up (rows 0..39 live in wave 0), write per-block
    // histogram contribution. No atomics, no fences.
    if (tid < NH) {
        float u_sum = (float)sAcc * INVUQ;
        float u_prev = __shfl_up(u_sum, 1);
        if ((tid % NBINS) == 0) u_prev = 0.0f;
        parts[tid * nparts + blockIdx.x] = 0.1f * ((float)nAcc - u_sum + u_prev);
    }
}

__global__ void __launch_bounds__(1024) wb_final(const float4* __restrict__ parts4,
                                                 const float* __restrict__ bary,
                                                 float* __restrict__ out, int nparts) {
    __shared__ float hist[NH];
    __shared__ float bsh[NBINS];
    __shared__ float losses[NG];

    if (threadIdx.x < NBINS) {
        float b = bary[threadIdx.x];
        bsh[threadIdx.x] = b;
        out[1 + threadIdx.x] = b;     // tuple output: bary_est passthrough
    }

    // float4 reduce of [40][nparts] partials: each float4 = 4 partials, same bin
    const int q4 = nparts >> 2;
    int wave = threadIdx.x >> 6, lane = threadIdx.x & 63;
    for (int j = wave; j < NH; j += 16) {
        float s = 0.0f;
        for (int i = lane; i < q4; i += 64) {
            float4 v = parts4[j * q4 + i];
            s += (v.x + v.y) + (v.z + v.w);
        }
        #pragma unroll
        for (int off = 32; off; off >>= 1) s += __shfl_down(s, off);
        if (lane == 0) hist[j] = s;
    }
    __syncthreads();

    // 4 lanes (one per group), uniform control flow, all arrays register-resident
    if (threadIdx.x < NG) {
        const int gI = threadIdx.x;
        float h[NBINS];
        float s = 0.0f;
        #pragma unroll
        for (int j = 0; j < NBINS; ++j) { h[j] = hist[gI * NBINS + j] + 0.0001f; s += h[j]; }
        #pragma unroll
        for (int j = 0; j < NBINS; ++j) h[j] /= s;
        float s2 = 0.0f;                    // genHists renorm (fp no-op, kept for fidelity)
        #pragma unroll
        for (int j = 0; j < NBINS; ++j) s2 += h[j];
        #pragma unroll
        for (int j = 0; j < NBINS; ++j) h[j] /= s2;

        float cdfa[NBINS], cdfb[NBINS];
        float acc = 0.0f;
        #pragma unroll
        for (int j = 0; j < NBINS; ++j) { acc += h[j]; cdfa[j] = acc; }
        acc = 0.0f;
        #pragma unroll
        for (int j = 0; j < NBINS; ++j) { acc += bsh[j]; cdfb[j] = acc; }
        // top-equalization reproduces searchsorted clip at q > min(top_a, top_b)
        float T = fmaxf(cdfa[NBINS - 1], cdfb[NBINS - 1]);
        cdfa[NBINS - 1] = T;
        cdfb[NBINS - 1] = T;

        // sum over merged quantile intervals == sum of pairwise interval overlaps
        float loss = 0.0f, lo_a = 0.0f;
        #pragma unroll
        for (int i = 0; i < NBINS; ++i) {
            float hi_a = cdfa[i];
            float lo_b = 0.0f;
            #pragma unroll
            for (int j = 0; j < NBINS; ++j) {
                float hi_b = cdfb[j];
                float ov = fminf(hi_a, hi_b) - fmaxf(lo_a, lo_b);
                float w = (float)((i - j) * (i - j));
                loss += fmaxf(ov, 0.0f) * w;
                lo_b = hi_b;
            }
            lo_a = hi_a;
        }
        losses[gI] = loss;
    }
    __syncthreads();
    if (threadIdx.x == 0)
        out[0] = losses[0] + losses[1] + losses[2] + losses[3];
}

extern "C" void kernel_launch(void* const* d_in, const int* in_sizes, int n_in,
                              void* d_out, int out_size, void* d_ws, size_t ws_size,
                              hipStream_t stream) {
    const float* acts   = (const float*)d_in[0];
    const float* bary   = (const float*)d_in[1];
    const int*   labels = (const int*)d_in[2];
    float* outp  = (float*)d_out;
    float* parts = (float*)d_ws;           // [NH][NBLOCKS] = 327 KB, fully rewritten
    int N  = in_sizes[0];
    int n4 = N >> 2;

    wb_hist<<<NBLOCKS, TPB, 0, stream>>>((const f32x4*)acts, (const i32x4*)labels,
                                         acts, labels, parts, n4, N, NBLOCKS);
    wb_final<<<1, 1024, 0, stream>>>((const float4*)parts, bary, outp, NBLOCKS);
}